// Round 1
// baseline (119.596 us; speedup 1.0000x reference)
//
#include <hip/hip_runtime.h>
#include <hip/hip_bf16.h>

#define N_NODE 50000
#define N_USED 50000
#define N_EDGE 800000
#define N_REL  8

typedef __bf16 bf16x8 __attribute__((ext_vector_type(8)));
typedef float  f32x4  __attribute__((ext_vector_type(4)));

__device__ __forceinline__ float bf_lo(unsigned u) {
    union { unsigned i; float f; } v; v.i = u << 16; return v.f;
}
__device__ __forceinline__ float bf_hi(unsigned u) {
    union { unsigned i; float f; } v; v.i = u & 0xffff0000u; return v.f;
}

// ---- stage 1a: x (fp32, [N_USED][128]) -> xb (bf16, same layout) ----
__global__ __launch_bounds__(256) void k_cvt_x(const float* __restrict__ x,
                                               __hip_bfloat16* __restrict__ xb) {
    int i = blockIdx.x * 256 + threadIdx.x;       // 1.6M threads, 4 floats each
    float4 v = reinterpret_cast<const float4*>(x)[i];
    __hip_bfloat16 h0 = __float2bfloat16(v.x);
    __hip_bfloat16 h1 = __float2bfloat16(v.y);
    __hip_bfloat16 h2 = __float2bfloat16(v.z);
    __hip_bfloat16 h3 = __float2bfloat16(v.w);
    ushort4 o;
    o.x = *reinterpret_cast<unsigned short*>(&h0);
    o.y = *reinterpret_cast<unsigned short*>(&h1);
    o.z = *reinterpret_cast<unsigned short*>(&h2);
    o.w = *reinterpret_cast<unsigned short*>(&h3);
    reinterpret_cast<ushort4*>(xb)[i] = o;
}

// ---- stage 1b: W [r][c][h] fp32 -> Wt [r][h][c] bf16 ----
__global__ __launch_bounds__(256) void k_cvt_w(const float* __restrict__ w,
                                               __hip_bfloat16* __restrict__ wt) {
    int i = blockIdx.x * 256 + threadIdx.x;       // 131072 elems
    int r = i >> 14, c = (i >> 7) & 127, h = i & 127;
    wt[(((size_t)r << 7) + h) * 128 + c] = __float2bfloat16(w[i]);
}

// ---- stage 2: tf[r][n][h] = sum_c xb[n][c] * W[r][c][h], bf16 out ----
// block = 256 threads = 4 waves; each wave does 64 rows x 128 cols; K=128.
__global__ __launch_bounds__(256) void k_gemm(const __hip_bfloat16* __restrict__ xb,
                                              const __hip_bfloat16* __restrict__ wt,
                                              __hip_bfloat16* __restrict__ tf) {
    const int lane = threadIdx.x & 63;
    const int wid  = threadIdx.x >> 6;
    const int r    = blockIdx.y;
    const int row0 = blockIdx.x * 256 + wid * 64;
    const int rlo  = lane & 15;
    const int k0   = (lane >> 4) * 8;

    // A fragments: row = row0 + rc*16 + (lane&15), k = kc*32 + (lane>>4)*8 + j
    bf16x8 a[4][4];
#pragma unroll
    for (int rc = 0; rc < 4; ++rc) {
        int row = row0 + rc * 16 + rlo;
        if (row >= N_USED) row = N_USED - 1;          // clamp; discarded at store
        const __hip_bfloat16* p = xb + (size_t)row * 128 + k0;
#pragma unroll
        for (int kc = 0; kc < 4; ++kc)
            a[rc][kc] = *reinterpret_cast<const bf16x8*>(p + kc * 32);
    }

    f32x4 acc[4][8];
    const f32x4 zero = {0.f, 0.f, 0.f, 0.f};
#pragma unroll
    for (int rc = 0; rc < 4; ++rc)
#pragma unroll
        for (int nc = 0; nc < 8; ++nc)
            acc[rc][nc] = zero;

    const __hip_bfloat16* wr = wt + (size_t)r * 16384;   // [h][c] layout
#pragma unroll
    for (int nc = 0; nc < 8; ++nc) {
#pragma unroll
        for (int kc = 0; kc < 4; ++kc) {
            // B fragment: col(h) = nc*16 + (lane&15), k = kc*32 + (lane>>4)*8 + j
            bf16x8 b = *reinterpret_cast<const bf16x8*>(
                wr + ((size_t)(nc * 16 + rlo)) * 128 + kc * 32 + k0);
#pragma unroll
            for (int rc = 0; rc < 4; ++rc)
                acc[rc][nc] = __builtin_amdgcn_mfma_f32_16x16x32_bf16(
                    a[rc][kc], b, acc[rc][nc], 0, 0, 0);
        }
    }

    // C/D layout: col = lane&15, row = (lane>>4)*4 + j
#pragma unroll
    for (int rc = 0; rc < 4; ++rc) {
#pragma unroll
        for (int j = 0; j < 4; ++j) {
            int row = row0 + rc * 16 + (lane >> 4) * 4 + j;
            if (row < N_USED) {
                __hip_bfloat16* dst = tf + ((size_t)r * N_USED + row) * 128 + rlo;
#pragma unroll
                for (int nc = 0; nc < 8; ++nc)
                    dst[nc * 16] = __float2bfloat16(acc[rc][nc][j]);
            }
        }
    }
}

// ---- stage 3: CSR segment sum over gathered tf rows ----
// one wave per node; lane handles 2 h-values (one packed uint = 2 bf16)
__global__ __launch_bounds__(256) void k_segsum(const __hip_bfloat16* __restrict__ tf,
                                                const int* __restrict__ ptr,
                                                const int* __restrict__ idx,
                                                const int* __restrict__ rel,
                                                float* __restrict__ out) {
    const int lane = threadIdx.x & 63;
    const int s = blockIdx.x * 4 + (threadIdx.x >> 6);
    if (s >= N_NODE) return;
    const int e0 = ptr[s], e1 = ptr[s + 1];
    float ax = 0.f, ay = 0.f;
    const unsigned* base = reinterpret_cast<const unsigned*>(tf) + lane;
    int e = e0;
    for (; e + 4 <= e1; e += 4) {
        size_t o0 = ((size_t)rel[e]     * N_USED + idx[e])     * 64;
        size_t o1 = ((size_t)rel[e + 1] * N_USED + idx[e + 1]) * 64;
        size_t o2 = ((size_t)rel[e + 2] * N_USED + idx[e + 2]) * 64;
        size_t o3 = ((size_t)rel[e + 3] * N_USED + idx[e + 3]) * 64;
        unsigned u0 = base[o0];
        unsigned u1 = base[o1];
        unsigned u2 = base[o2];
        unsigned u3 = base[o3];
        ax += bf_lo(u0); ay += bf_hi(u0);
        ax += bf_lo(u1); ay += bf_hi(u1);
        ax += bf_lo(u2); ay += bf_hi(u2);
        ax += bf_lo(u3); ay += bf_hi(u3);
    }
    for (; e < e1; ++e) {
        unsigned u = base[((size_t)rel[e] * N_USED + idx[e]) * 64];
        ax += bf_lo(u); ay += bf_hi(u);
    }
    float2 o = {ax, ay};
    reinterpret_cast<float2*>(out + (size_t)s * 128)[lane] = o;
}

// ---- fallback (tiny workspace): direct fp32 compute, slow but correct ----
__global__ __launch_bounds__(256) void k_direct(const float* __restrict__ x,
                                                const float* __restrict__ w,
                                                const int* __restrict__ ptr,
                                                const int* __restrict__ idx,
                                                const int* __restrict__ rel,
                                                float* __restrict__ out) {
    const int lane = threadIdx.x & 63;
    const int s = blockIdx.x * 4 + (threadIdx.x >> 6);
    if (s >= N_NODE) return;
    const int e0 = ptr[s], e1 = ptr[s + 1];
    const int h = lane * 2;
    float ax = 0.f, ay = 0.f;
    for (int e = e0; e < e1; ++e) {
        const float* xr = x + (size_t)idx[e] * 128;
        const float* wr = w + (size_t)rel[e] * 16384 + h;
        for (int c = 0; c < 128; ++c) {
            float xv = xr[c];
            ax += xv * wr[(size_t)c * 128];
            ay += xv * wr[(size_t)c * 128 + 1];
        }
    }
    float2 o = {ax, ay};
    reinterpret_cast<float2*>(out + (size_t)s * 128)[lane] = o;
}

extern "C" void kernel_launch(void* const* d_in, const int* in_sizes, int n_in,
                              void* d_out, int out_size, void* d_ws, size_t ws_size,
                              hipStream_t stream) {
    const float* x   = (const float*)d_in[0];
    const float* w   = (const float*)d_in[1];
    const int*   ptr = (const int*)d_in[2];
    const int*   idx = (const int*)d_in[3];
    const int*   rel = (const int*)d_in[4];
    float*       out = (float*)d_out;

    const size_t off_xb = 0;                       // 12,800,000 B
    const size_t off_wt = 12800000;                //    262,144 B
    const size_t off_tf = 13062144;                // 102,400,000 B
    const size_t need   = off_tf + (size_t)N_REL * N_USED * 128 * 2;

    if (ws_size >= need) {
        __hip_bfloat16* xb = (__hip_bfloat16*)((char*)d_ws + off_xb);
        __hip_bfloat16* wt = (__hip_bfloat16*)((char*)d_ws + off_wt);
        __hip_bfloat16* tf = (__hip_bfloat16*)((char*)d_ws + off_tf);
        k_cvt_x<<<6250, 256, 0, stream>>>(x, xb);            // 6.4M elems / 4
        k_cvt_w<<<512, 256, 0, stream>>>(w, wt);             // 131072 elems
        k_gemm<<<dim3(196, 8), 256, 0, stream>>>(xb, wt, tf);
        k_segsum<<<12500, 256, 0, stream>>>(tf, ptr, idx, rel, out);
    } else {
        k_direct<<<12500, 256, 0, stream>>>(x, w, ptr, idx, rel, out);
    }
}